// Round 11
// baseline (1160.011 us; speedup 1.0000x reference)
//
#include <hip/hip_runtime.h>
#include <stdint.h>

#define B_ROWS 16384
#define D_DIM  2048
#define H_DIM  512
#define BM 64
#define BN 64
#define BK 32
#define CHUNKS 8
#define KTILES 64
#define NRB (B_ROWS / BM)     // 256 row-blocks; grid = 256*8 = 2048

typedef __attribute__((ext_vector_type(4))) float  f32x4;
typedef __attribute__((ext_vector_type(8))) __bf16 bf16x8;

// ---- LDS geometry (bytes). k-granule-major: [g][row] of 16B (8 bf16 = k g*8..g*8+7)
#define AST   1088                    // A per-g region stride (1024 + 64 pad -> 2-way writes)
#define AMAT  (4 * AST)               // per (mat,hilo) = 4352
#define A_TOTAL (8 * AMAT)            // 4 mats x 2 hilo = 34816
#define BST   1024
#define BMAT  (4 * BST)
#define B_OFF A_TOTAL
#define SMEM_BYTES (A_TOTAL + 6 * BMAT)   // 34816 + 24576 = 59392

// ws layout (floats): [0..511] q0 ; [512..512+131072) S[row][8] ; then weights hi/lo
#define WS_S   512
#define WS_W_F 131584                        // float offset of weight planes (16B aligned)
#define WS_W_U4 (WS_W_F / 4)                 // uint4 offset
// weight planes: uint4 index ((mat*2+h)*256 + gg)*512 + c   (3 mats, 256 granules, 512 cols)
#define WS_NEED_BYTES (((size_t)WS_W_F + 3ull * 2 * 256 * 512 * 4) * 4)   // 13,109,248

#if defined(__has_builtin)
#  if __has_builtin(__builtin_amdgcn_global_load_lds)
#    define HAVE_GLL 1
#  endif
#endif
#ifndef HAVE_GLL
#  define HAVE_GLL 0
#endif

__device__ __forceinline__ uint32_t hibits(float x) {
    // round-to-nearest (ties away) to bf16, kept as masked fp32 bit pattern
    return (__float_as_uint(x) + 0x8000u) & 0xFFFF0000u;
}

// ---------------------------------------------------------------------------
__global__ void zero_kernel(float* __restrict__ S) {
    const int i = blockIdx.x * 256 + threadIdx.x;     // 32768 float4s
    ((float4*)S)[i] = make_float4(0.f, 0.f, 0.f, 0.f);
}

// q0 = gw0 @ Wq + bq -> ws[0..511]
__global__ void q0_kernel(const float* __restrict__ gw0, const float* __restrict__ Wq,
                          const float* __restrict__ bq, float* __restrict__ q0out) {
    __shared__ float red[256];
    const int c  = blockIdx.x * 16 + (threadIdx.x & 15);
    const int dq = threadIdx.x >> 4;
    float s = 0.f;
#pragma unroll 8
    for (int i = 0; i < 128; ++i) {
        const int d = dq * 128 + i;
        s = fmaf(gw0[d], Wq[(size_t)d * H_DIM + c], s);
    }
    red[threadIdx.x] = s;
    __syncthreads();
    if (threadIdx.x < 16) {
        float t = 0.f;
#pragma unroll
        for (int q = 0; q < 16; ++q) t += red[q * 16 + threadIdx.x];
        q0out[c] = t + bq[c];
    }
}

// ---------------------------------------------------------------------------
// One-time weight split: W[d][c] f32 -> hi/lo bf16 granule-major planes in ws.
// Same packing as the in-kernel B staging (RTN hibits), so numerics identical.
// ---------------------------------------------------------------------------
__global__ void presplit_w(const float* __restrict__ Wkv, const float* __restrict__ Wkt,
                           const float* __restrict__ Wq, uint4* __restrict__ wsW) {
    const int bx  = blockIdx.x;               // 1536 = 3 mats * 256 gg * 2 halves
    const int mat = bx >> 9;
    const int rem = bx & 511;
    const int gg  = rem >> 1;                 // d-granule 0..255
    const int c   = (rem & 1) * 256 + threadIdx.x;
    const float* W = (mat == 0) ? Wkv : (mat == 1) ? Wkt : Wq;
    const float* p = W + (size_t)gg * 8 * H_DIM + c;
    uint32_t h[8]; float el[8];
#pragma unroll
    for (int i = 0; i < 8; ++i) {
        const float x = p[(size_t)i * H_DIM];
        h[i]  = hibits(x);
        el[i] = x - __uint_as_float(h[i]);
    }
    uint4 H, L;
    H.x = (h[0] >> 16) | h[1];  H.y = (h[2] >> 16) | h[3];
    H.z = (h[4] >> 16) | h[5];  H.w = (h[6] >> 16) | h[7];
    L.x = (hibits(el[0]) >> 16) | hibits(el[1]);  L.y = (hibits(el[2]) >> 16) | hibits(el[3]);
    L.z = (hibits(el[4]) >> 16) | hibits(el[5]);  L.w = (hibits(el[6]) >> 16) | hibits(el[7]);
    wsW[((size_t)(mat * 2 + 0) * 256 + gg) * 512 + c] = H;
    wsW[((size_t)(mat * 2 + 1) * 256 + gg) * 512 + c] = L;
}

// ---------------------------------------------------------------------------
// Per (row-block, chunk): 4 GEMM tiles via split-bf16 MFMA, contract to 8
// per-row scalar partials, atomicAdd into S[row][8].
// PRE=true: B staged by global_load_lds from pre-split ws planes (no VALU).
// ---------------------------------------------------------------------------
template <bool PRE>
__global__ __launch_bounds__(256, 2)
void dqa_mfma(const float* __restrict__ x_v, const float* __restrict__ x_t,
              const float* __restrict__ e_v, const float* __restrict__ e_t,
              const float* __restrict__ Wq,  const float* __restrict__ bq,
              const float* __restrict__ Wk_v, const float* __restrict__ bk_v,
              const float* __restrict__ Wk_t, const float* __restrict__ bk_t,
              const uint4* __restrict__ wsW, float* __restrict__ ws) {
    __shared__ char smem[SMEM_BYTES];

    const int tid   = threadIdx.x;
    const int rb    = blockIdx.x & (NRB - 1);
    const int ch    = blockIdx.x >> 8;            // 0..7
    const int rbase = rb * BM;
    const int cbase = ch * BN;

    const int lane = tid & 63;
    const int wv   = tid >> 6;                    // wave 0..3
    const int wm   = wv >> 1, wn = wv & 1;        // 2M x 2N
    const int l15  = lane & 15, lg = lane >> 4;   // frag col/row group, k-granule

    // staging assignments
    const int arow = tid >> 2, ag = tid & 3;      // A: 64 rows x 4 granules
    const int bcol = tid & 63, bg = tid >> 6;     // B: 64 cols x 4 granules (non-PRE)

    const float* Amats[4] = {x_v, x_t, e_v, e_t};

    f32x4 acc[4][2][2];                           // [outmat][mrep][nrep]
#pragma unroll
    for (int m = 0; m < 4; ++m)
#pragma unroll
        for (int i = 0; i < 2; ++i)
#pragma unroll
            for (int j = 0; j < 2; ++j) acc[m][i][j] = (f32x4)0.f;

    // precomputed frag read offsets (lane-dependent parts)
    const int aro = lg * AST + (wm * 32 + l15) * 16;            // + mrep*256 + (mat*2+h)*AMAT
    const int bro = B_OFF + lg * BST + (wn * 32 + l15) * 16;    // + nrep*256 + (bmat*2+h)*BMAT

    for (int kt = 0; kt < KTILES; ++kt) {
        const int kb = kt * BK;
        __syncthreads();
        // ---- stage A (4 input mats): thread -> (arow, granule ag), 8 k-values
        {
            const size_t goff = (size_t)(rbase + arow) * D_DIM + kb + ag * 8;
            const int    aoff = ag * AST + arow * 16;
#pragma unroll
            for (int m = 0; m < 4; ++m) {
                const float4 v0 = *(const float4*)(Amats[m] + goff);
                const float4 v1 = *(const float4*)(Amats[m] + goff + 4);
                uint32_t h0 = hibits(v0.x), h1 = hibits(v0.y), h2 = hibits(v0.z), h3 = hibits(v0.w);
                uint32_t h4 = hibits(v1.x), h5 = hibits(v1.y), h6 = hibits(v1.z), h7 = hibits(v1.w);
                uint4 H;
                H.x = (h0 >> 16) | h1;  H.y = (h2 >> 16) | h3;
                H.z = (h4 >> 16) | h5;  H.w = (h6 >> 16) | h7;
                float l0 = v0.x - __uint_as_float(h0), l1 = v0.y - __uint_as_float(h1);
                float l2 = v0.z - __uint_as_float(h2), l3 = v0.w - __uint_as_float(h3);
                float l4 = v1.x - __uint_as_float(h4), l5 = v1.y - __uint_as_float(h5);
                float l6 = v1.z - __uint_as_float(h6), l7 = v1.w - __uint_as_float(h7);
                uint4 L;
                L.x = (hibits(l0) >> 16) | hibits(l1);  L.y = (hibits(l2) >> 16) | hibits(l3);
                L.z = (hibits(l4) >> 16) | hibits(l5);  L.w = (hibits(l6) >> 16) | hibits(l7);
                *(uint4*)(smem + (m * 2 + 0) * AMAT + aoff) = H;
                *(uint4*)(smem + (m * 2 + 1) * AMAT + aoff) = L;
            }
        }
        // ---- stage B (3 weight mats, hi/lo)
        if constexpr (PRE) {
            // copy pre-split fragments: per (mat,half): wave wv -> granule, lane -> col.
            // LDS layout identical to non-PRE: B_OFF + mh*4096 + g*1024 + col*16
#pragma unroll
            for (int mh = 0; mh < 6; ++mh) {
                const uint4* src = wsW + ((size_t)(mh * 256 + (kt << 2) + wv) << 9) + cbase + lane;
#if HAVE_GLL
                __builtin_amdgcn_global_load_lds(
                    (const __attribute__((address_space(1))) void*)(const void*)src,
                    (__attribute__((address_space(3))) void*)(void*)(smem + B_OFF + mh * 4096 + wv * 1024),
                    16, 0, 0);
#else
                *(uint4*)(smem + B_OFF + mh * 4096 + wv * 1024 + lane * 16) = *src;
#endif
            }
        } else {
            const float* Bmats[3] = {Wk_v, Wk_t, Wq};
            const int boff = B_OFF + bg * BST + bcol * 16;
#pragma unroll
            for (int m = 0; m < 3; ++m) {
                const float* wp = Bmats[m] + (size_t)(kb + bg * 8) * H_DIM + cbase + bcol;
                float e0 = wp[0 * H_DIM], e1 = wp[1 * H_DIM], e2 = wp[2 * H_DIM], e3 = wp[3 * H_DIM];
                float e4 = wp[4 * H_DIM], e5 = wp[5 * H_DIM], e6 = wp[6 * H_DIM], e7 = wp[7 * H_DIM];
                uint32_t h0 = hibits(e0), h1 = hibits(e1), h2 = hibits(e2), h3 = hibits(e3);
                uint32_t h4 = hibits(e4), h5 = hibits(e5), h6 = hibits(e6), h7 = hibits(e7);
                uint4 H;
                H.x = (h0 >> 16) | h1;  H.y = (h2 >> 16) | h3;
                H.z = (h4 >> 16) | h5;  H.w = (h6 >> 16) | h7;
                float l0 = e0 - __uint_as_float(h0), l1 = e1 - __uint_as_float(h1);
                float l2 = e2 - __uint_as_float(h2), l3 = e3 - __uint_as_float(h3);
                float l4 = e4 - __uint_as_float(h4), l5 = e5 - __uint_as_float(h5);
                float l6 = e6 - __uint_as_float(h6), l7 = e7 - __uint_as_float(h7);
                uint4 L;
                L.x = (hibits(l0) >> 16) | hibits(l1);  L.y = (hibits(l2) >> 16) | hibits(l3);
                L.z = (hibits(l4) >> 16) | hibits(l5);  L.w = (hibits(l6) >> 16) | hibits(l7);
                *(uint4*)(smem + (m * 2 + 0) * BMAT + boff) = H;
                *(uint4*)(smem + (m * 2 + 1) * BMAT + boff) = L;
            }
        }
        __syncthreads();

        // ---- A fragments (held), B per nrep, 48 MFMAs
        bf16x8 af[4][2][2];                        // [mat][hilo][mrep]
#pragma unroll
        for (int m = 0; m < 4; ++m)
#pragma unroll
            for (int h = 0; h < 2; ++h)
#pragma unroll
                for (int mr = 0; mr < 2; ++mr)
                    af[m][h][mr] = __builtin_bit_cast(bf16x8,
                        *(const uint4*)(smem + (m * 2 + h) * AMAT + aro + mr * 256));

#pragma unroll
        for (int nr = 0; nr < 2; ++nr) {
            bf16x8 bfr[3][2];
#pragma unroll
            for (int m = 0; m < 3; ++m)
#pragma unroll
                for (int h = 0; h < 2; ++h)
                    bfr[m][h] = __builtin_bit_cast(bf16x8,
                        *(const uint4*)(smem + (m * 2 + h) * BMAT + bro + nr * 256));
#pragma unroll
            for (int m = 0; m < 4; ++m) {
                const int bmap = (m < 2) ? m : 2;
#pragma unroll
                for (int mr = 0; mr < 2; ++mr) {
                    f32x4 c = acc[m][mr][nr];
                    c = __builtin_amdgcn_mfma_f32_16x16x32_bf16(af[m][0][mr], bfr[bmap][0], c, 0, 0, 0);
                    c = __builtin_amdgcn_mfma_f32_16x16x32_bf16(af[m][0][mr], bfr[bmap][1], c, 0, 0, 0);
                    c = __builtin_amdgcn_mfma_f32_16x16x32_bf16(af[m][1][mr], bfr[bmap][0], c, 0, 0, 0);
                    acc[m][mr][nr] = c;
                }
            }
        }
    }

    // ---- epilogue: add key biases, form 8 per-row scalar partials, reduce, atomadd
    float bkvc[2], bktc[2], bqc[2], q0c[2];
#pragma unroll
    for (int nr = 0; nr < 2; ++nr) {
        const int col = cbase + wn * 32 + nr * 16 + l15;
        bkvc[nr] = bk_v[col];  bktc[nr] = bk_t[col];
        bqc[nr]  = bq[col];    q0c[nr]  = ws[col];    // q0 (includes bq)
    }
    float* S = ws + WS_S;
#pragma unroll
    for (int mr = 0; mr < 2; ++mr) {
#pragma unroll
        for (int r = 0; r < 4; ++r) {
            const float kv0 = acc[0][mr][0][r] + bkvc[0], kv1 = acc[0][mr][1][r] + bkvc[1];
            const float kt0 = acc[1][mr][0][r] + bktc[0], kt1 = acc[1][mr][1][r] + bktc[1];
            const float pv0 = acc[2][mr][0][r],           pv1 = acc[2][mr][1][r];
            const float pt0 = acc[3][mr][0][r],           pt1 = acc[3][mr][1][r];
            float s0 = kv0 * pv0 + kv1 * pv1;
            float s1 = kv0 * pt0 + kv1 * pt1;
            float s2 = kt0 * pv0 + kt1 * pv1;
            float s3 = kt0 * pt0 + kt1 * pt1;
            float s4 = kv0 * bqc[0] + kv1 * bqc[1];
            float s5 = kt0 * bqc[0] + kt1 * bqc[1];
            float s6 = kv0 * q0c[0] + kv1 * q0c[1];
            float s7 = kt0 * q0c[0] + kt1 * q0c[1];
#pragma unroll
            for (int off = 1; off <= 8; off <<= 1) {
                s0 += __shfl_xor(s0, off); s1 += __shfl_xor(s1, off);
                s2 += __shfl_xor(s2, off); s3 += __shfl_xor(s3, off);
                s4 += __shfl_xor(s4, off); s5 += __shfl_xor(s5, off);
                s6 += __shfl_xor(s6, off); s7 += __shfl_xor(s7, off);
            }
            if (l15 == 0) {
                const int row = rbase + wm * 32 + mr * 16 + lg * 4 + r;
                atomicAdd(&S[row * 8 + 0], s0); atomicAdd(&S[row * 8 + 1], s1);
                atomicAdd(&S[row * 8 + 2], s2); atomicAdd(&S[row * 8 + 3], s3);
                atomicAdd(&S[row * 8 + 4], s4); atomicAdd(&S[row * 8 + 5], s5);
                atomicAdd(&S[row * 8 + 6], s6); atomicAdd(&S[row * 8 + 7], s7);
            }
        }
    }
}

// ---------------------------------------------------------------------------
__global__ void final_kernel(const float* __restrict__ S, float* __restrict__ out) {
    const int row = blockIdx.x * 256 + threadIdx.x;
    const float* s = S + row * 8;
    const float svv = s[0], svt = s[1], stv = s[2], stt = s[3], svb = s[4], stb = s[5];
    float dv = s[6], dt = s[7];
    float a0 = 0.f, a1 = 0.f;
#pragma unroll
    for (int i = 0; i <= 4; ++i) {
        if (i) { dv = a0 * svv + a1 * svt + svb; dt = a0 * stv + a1 * stt + stb; }
        const float m  = fmaxf(dv, dt);
        const float ev = __expf(dv - m), et = __expf(dt - m);
        const float inv = 1.f / (ev + et);
        a0 = ev * inv; a1 = et * inv;
    }
    out[2 * row + 0] = a0;
    out[2 * row + 1] = a1;
}

extern "C" void kernel_launch(void* const* d_in, const int* in_sizes, int n_in,
                              void* d_out, int out_size, void* d_ws, size_t ws_size,
                              hipStream_t stream) {
    const float* x_v  = (const float*)d_in[0];
    const float* x_t  = (const float*)d_in[1];
    const float* e_v  = (const float*)d_in[2];
    const float* e_t  = (const float*)d_in[3];
    const float* gw0  = (const float*)d_in[4];
    const float* Wq   = (const float*)d_in[5];
    const float* bq   = (const float*)d_in[6];
    const float* Wk_v = (const float*)d_in[7];
    const float* bk_v = (const float*)d_in[8];
    const float* Wk_t = (const float*)d_in[9];
    const float* bk_t = (const float*)d_in[10];
    float* ws  = (float*)d_ws;
    float* out = (float*)d_out;

    const bool pre = (ws_size >= WS_NEED_BYTES);

    zero_kernel<<<128, 256, 0, stream>>>(ws + WS_S);
    q0_kernel<<<32, 256, 0, stream>>>(gw0, Wq, bq, ws);
    if (pre) {
        uint4* wsW = (uint4*)(ws + WS_W_F);
        presplit_w<<<1536, 256, 0, stream>>>(Wk_v, Wk_t, Wq, wsW);
        dqa_mfma<true><<<NRB * CHUNKS, 256, 0, stream>>>(x_v, x_t, e_v, e_t, Wq, bq,
                                                         Wk_v, bk_v, Wk_t, bk_t, wsW, ws);
    } else {
        dqa_mfma<false><<<NRB * CHUNKS, 256, 0, stream>>>(x_v, x_t, e_v, e_t, Wq, bq,
                                                          Wk_v, bk_v, Wk_t, bk_t, nullptr, ws);
    }
    final_kernel<<<B_ROWS / 256, 256, 0, stream>>>(ws + WS_S, out);
}